// Round 1
// baseline (229.122 us; speedup 1.0000x reference)
//
#include <hip/hip_runtime.h>

#define NB 32          // batch
#define NT 1024        // input time steps
#define ND 384         // feature dim
#define ND4 (ND / 4)   // 96 float4 per frame

// One block per batch: inclusive scan of durations[b, :] into csum[b, :].
__global__ void scan_kernel(const int* __restrict__ dur, int* __restrict__ csum) {
    __shared__ int s[NT];
    const int b = blockIdx.x;
    const int t = threadIdx.x;
    s[t] = dur[b * NT + t];
    __syncthreads();
    #pragma unroll
    for (int off = 1; off < NT; off <<= 1) {
        int add = (t >= off) ? s[t - off] : 0;
        __syncthreads();
        s[t] += add;
        __syncthreads();
    }
    csum[b * NT + t] = s[t];
}

// grid = (blocks_x, NB). Each block caches csum row for its batch in LDS,
// then grid-strides over float4 elements of that batch's output slab.
__global__ void __launch_bounds__(256)
gather_kernel(const float4* __restrict__ enc,
              const int* __restrict__ csum,
              float4* __restrict__ out,
              int max_len, int f4_per_batch) {
    __shared__ int sc[NT];
    const int b = blockIdx.y;
    for (int i = threadIdx.x; i < NT; i += blockDim.x)
        sc[i] = csum[b * NT + i];
    __syncthreads();
    const int total = sc[NT - 1];

    const size_t enc_base = (size_t)b * NT * ND4;
    const size_t out_base = (size_t)b * max_len * ND4;
    const int stride = gridDim.x * blockDim.x;

    for (int j = blockIdx.x * blockDim.x + threadIdx.x; j < f4_per_batch; j += stride) {
        const int p  = j / ND4;          // output frame within batch
        const int d4 = j - p * ND4;      // float4 index within frame
        float4 val;
        if (p < total) {
            // first t with csum[t] > p  (searchsorted side='right');
            // p < total == csum[NT-1] guarantees lo <= NT-1
            int lo = 0, hi = NT - 1;
            while (lo < hi) {
                int mid = (lo + hi) >> 1;
                if (sc[mid] <= p) lo = mid + 1; else hi = mid;
            }
            val = enc[enc_base + (size_t)lo * ND4 + d4];
        } else {
            val = make_float4(0.f, 0.f, 0.f, 0.f);  // zero-pad past total
        }
        out[out_base + j] = val;
    }
}

extern "C" void kernel_launch(void* const* d_in, const int* in_sizes, int n_in,
                              void* d_out, int out_size, void* d_ws, size_t ws_size,
                              hipStream_t stream) {
    const float* enc = (const float*)d_in[0];
    const int*   dur = (const int*)d_in[1];
    float* out = (float*)d_out;

    const int max_len = out_size / (NB * ND);   // out_size = NB*max_len*ND
    int* csum = (int*)d_ws;                      // 32*1024*4 = 128 KB scratch

    scan_kernel<<<NB, NT, 0, stream>>>(dur, csum);

    const int f4pb = max_len * ND4;
    dim3 grid(64, NB);
    gather_kernel<<<grid, 256, 0, stream>>>(
        (const float4*)enc, csum, (float4*)out, max_len, f4pb);
}